// Round 7
// baseline (249.326 us; speedup 1.0000x reference)
//
#include <hip/hip_runtime.h>
#include <hip/hip_bf16.h>

// BitNetAttention: B=2,S=2048,HID=1024,NH=16,HD=64
#define NB 2
#define NS 2048
#define NHID 1024
#define NHEAD 16
#define NHD 64
#define NTOK (NB*NS)        // 4096
#define WELEM (NHID*NHID)   // 1048576

typedef unsigned short u16;
typedef __attribute__((ext_vector_type(4))) float floatx4;
typedef __attribute__((ext_vector_type(16))) float floatx16;
typedef __attribute__((ext_vector_type(8))) __bf16 bf16x8;
typedef __attribute__((ext_vector_type(8))) unsigned short ushort8;
typedef __attribute__((ext_vector_type(2))) unsigned uint2v;

__device__ __forceinline__ u16 f2bf(float f) {
  union { float f; unsigned u; } a; a.f = f;
  unsigned u = a.u;
  unsigned r = (u + 0x7fffu + ((u >> 16) & 1u)) >> 16;  // RNE
  return (u16)r;
}
__device__ __forceinline__ float bf2f(u16 s) {
  union { unsigned u; float f; } a; a.u = ((unsigned)s) << 16;
  return a.f;
}
__device__ __forceinline__ void gload16(const void* g, void* lds) {
  __builtin_amdgcn_global_load_lds(
      (const __attribute__((address_space(1))) unsigned int*)g,
      (__attribute__((address_space(3))) unsigned int*)lds, 16, 0, 0);
}
// v_permlane32_swap_b32 builtin: vdst[32:63] <-> src[0:31]; returns {vdst', src'}
__device__ __forceinline__ uint2v pl32(unsigned a, unsigned b) {
  return __builtin_amdgcn_permlane32_swap(a, b, false, false);
}
__device__ __forceinline__ float mergemax(float x) {
  uint2v r = pl32(__float_as_uint(x), __float_as_uint(x));
  return fmaxf(__uint_as_float(r[0]), __uint_as_float(r[1]));
}
__device__ __forceinline__ float mergesum(float x) {
  uint2v r = pl32(__float_as_uint(x), __float_as_uint(x));
  return __uint_as_float(r[0]) + __uint_as_float(r[1]);
}
__device__ __forceinline__ float tmax16(const floatx16& v) {
  float a = fmaxf(fmaxf(fmaxf(v[0], v[1]), fmaxf(v[2], v[3])),
                  fmaxf(fmaxf(v[4], v[5]), fmaxf(v[6], v[7])));
  float b = fmaxf(fmaxf(fmaxf(v[8], v[9]), fmaxf(v[10], v[11])),
                  fmaxf(fmaxf(v[12], v[13]), fmaxf(v[14], v[15])));
  return fmaxf(a, b);
}

// ---------------- scale reduction (fp64 for boundary fidelity) --------------
__global__ void k_init(double* sums) { if (threadIdx.x < 4) sums[threadIdx.x] = 0.0; }

__global__ void k_abssum(const float* __restrict__ wq, const float* __restrict__ wk,
                         const float* __restrict__ wv, const float* __restrict__ wo,
                         double* __restrict__ sums) {
  const float* srcs[4] = {wq, wk, wv, wo};
  const float* w = srcs[blockIdx.y];
  int idx = (blockIdx.x * 256 + threadIdx.x) * 16;
  float s = 0.f;
#pragma unroll
  for (int j = 0; j < 4; j++) {
    float4 v = *(const float4*)(w + idx + j * 4);
    s += fabsf(v.x) + fabsf(v.y) + fabsf(v.z) + fabsf(v.w);
  }
#pragma unroll
  for (int off = 32; off; off >>= 1) s += __shfl_down(s, off);
  __shared__ float ps[4];
  if ((threadIdx.x & 63) == 0) ps[threadIdx.x >> 6] = s;
  __syncthreads();
  if (threadIdx.x == 0) atomicAdd(&sums[blockIdx.y], (double)(ps[0] + ps[1] + ps[2] + ps[3]));
}

__global__ void k_quant(const float* __restrict__ wq, const float* __restrict__ wk,
                        const float* __restrict__ wv, const float* __restrict__ wo,
                        const double* __restrict__ sums, u16* __restrict__ wt) {
  const float* srcs[4] = {wq, wk, wv, wo};
  const float* w = srcs[blockIdx.y];
  u16* dst = wt + blockIdx.y * WELEM;
  float s = (float)(sums[blockIdx.y] / (double)WELEM) + 1e-5f;
  int idx = (blockIdx.x * 256 + threadIdx.x) * 4;
  float4 v = *(const float4*)(w + idx);
  float f[4] = {v.x, v.y, v.z, v.w};
  union { u16 ss[4]; uint2 u; } O;
#pragma unroll
  for (int j = 0; j < 4; j++) {
    float q = rintf(f[j] / s);            // round-half-even, matches np.round
    q = fminf(1.f, fmaxf(-1.f, q));
    O.ss[j] = f2bf(q);                    // ternary exact in bf16
  }
  *(uint2*)(dst + idx) = O.u;
}

// ---------------- fp32 -> bf16 hi/lo split ---------------------------------
__global__ void k_split(const float* __restrict__ x, u16* __restrict__ hi, u16* __restrict__ lo) {
  int idx = (blockIdx.x * 256 + threadIdx.x) * 4;
  float4 v = *(const float4*)(x + idx);
  float f[4] = {v.x, v.y, v.z, v.w};
  union { u16 s[4]; uint2 u; } H, L;
#pragma unroll
  for (int j = 0; j < 4; j++) {
    u16 hb = f2bf(f[j]);
    H.s[j] = hb;
    L.s[j] = f2bf(f[j] - bf2f(hb));
  }
  *(uint2*)(hi + idx) = H.u;
  *(uint2*)(lo + idx) = L.u;
}

// ---------------- GEMM: C[m,o] = sum_k (Ahi+Alo)[m,k] * W[o,k] --------------
template <int MODE>
__global__ __launch_bounds__(256) void k_gemm(
    const u16* __restrict__ Ahi, const u16* __restrict__ Alo,
    const u16* __restrict__ Wt, float* __restrict__ outf,
    u16* __restrict__ qh, u16* __restrict__ ql,
    u16* __restrict__ kh, u16* __restrict__ kl,
    u16* __restrict__ vh) {
  __shared__ __attribute__((aligned(16))) char GSM[49152];
  const int tid = threadIdx.x;
  const int wave = tid >> 6, lane = tid & 63;
  const int lr = lane & 15, lh = lane >> 4;
  const int bm = blockIdx.x, bn = blockIdx.y, z = blockIdx.z;
  const u16* W = Wt + (MODE == 0 ? z : 3) * WELEM;
  const int wr = wave >> 1, wc = wave & 1;

  floatx4 acc[4][4];
#pragma unroll
  for (int i = 0; i < 4; i++)
#pragma unroll
    for (int j = 0; j < 4; j++) acc[i][j] = (floatx4){0.f, 0.f, 0.f, 0.f};

  const int e0 = tid * 8;
  const int row0 = e0 >> 5, col0 = e0 & 31;

  // prologue: stage k-tile 0 into buf 0
#pragma unroll
  for (int it = 0; it < 2; ++it) {
    int row = row0 + it * 64;
    gload16(Ahi + (bm * 128 + row) * 1024 + col0, GSM + it * 4096 + wave * 1024);
    gload16(Alo + (bm * 128 + row) * 1024 + col0, GSM + 8192 + it * 4096 + wave * 1024);
    gload16(W   + (bn * 128 + row) * 1024 + col0, GSM + 16384 + it * 4096 + wave * 1024);
  }

  for (int kt = 0; kt < 32; ++kt) {  // K = 1024, 32-wide tiles
    __syncthreads();                 // stage(kt) complete; buf[kt-1] readers done
    const int cb = (kt & 1) * 24576;
    if (kt < 31) {
      const int nb2 = ((kt + 1) & 1) * 24576;
      const int k0 = (kt + 1) * 32;
#pragma unroll
      for (int it = 0; it < 2; ++it) {
        int row = row0 + it * 64;
        gload16(Ahi + (bm * 128 + row) * 1024 + k0 + col0, GSM + nb2 + it * 4096 + wave * 1024);
        gload16(Alo + (bm * 128 + row) * 1024 + k0 + col0, GSM + nb2 + 8192 + it * 4096 + wave * 1024);
        gload16(W   + (bn * 128 + row) * 1024 + k0 + col0, GSM + nb2 + 16384 + it * 4096 + wave * 1024);
      }
    }
    const u16* Ahp = (const u16*)(GSM + cb);
    const u16* Alp = (const u16*)(GSM + cb + 8192);
    const u16* Bp  = (const u16*)(GSM + cb + 16384);
    bf16x8 ah[4], al8[4], bfr[4];
#pragma unroll
    for (int mi = 0; mi < 4; mi++) {
      ah[mi]  = *(const bf16x8*)(Ahp + (wr * 64 + mi * 16 + lr) * 32 + lh * 8);
      al8[mi] = *(const bf16x8*)(Alp + (wr * 64 + mi * 16 + lr) * 32 + lh * 8);
    }
#pragma unroll
    for (int ni = 0; ni < 4; ni++)
      bfr[ni] = *(const bf16x8*)(Bp + (wc * 64 + ni * 16 + lr) * 32 + lh * 8);
#pragma unroll
    for (int mi = 0; mi < 4; mi++)
#pragma unroll
      for (int ni = 0; ni < 4; ni++) {
        acc[mi][ni] = __builtin_amdgcn_mfma_f32_16x16x32_bf16(ah[mi], bfr[ni], acc[mi][ni], 0, 0, 0);
        acc[mi][ni] = __builtin_amdgcn_mfma_f32_16x16x32_bf16(al8[mi], bfr[ni], acc[mi][ni], 0, 0, 0);
      }
  }

#pragma unroll
  for (int mi = 0; mi < 4; mi++)
#pragma unroll
    for (int ni = 0; ni < 4; ni++)
#pragma unroll
      for (int i = 0; i < 4; i++) {
        int row = bm * 128 + wr * 64 + mi * 16 + lh * 4 + i;  // token
        int col = bn * 128 + wc * 64 + ni * 16 + lr;          // out feature
        float v = acc[mi][ni][i];
        if (MODE == 1) {
          outf[row * 1024 + col] = v;
        } else {
          int b = row >> 11, s = row & 2047, hh = col >> 6, hd = col & 63;
          int dst = ((b * NHEAD + hh) * NS + s) * NHD + hd;
          u16 hb = f2bf(v);
          if (z == 0)      { qh[dst] = hb; ql[dst] = f2bf(v - bf2f(hb)); }
          else if (z == 1) { kh[dst] = hb; kl[dst] = f2bf(v - bf2f(hb)); }
          else             { vh[dst] = hb; }   // V: single bf16
        }
      }
}

// ---------------- V transpose: vh[bh][s][d] -> vt[bh][d][s] ----------------
__global__ void k_vtrans(const u16* __restrict__ vh, u16* __restrict__ vt) {
  const int bh = blockIdx.y;
  const int s0 = blockIdx.x * 64;
  const int t = threadIdx.x;
  const int d = t >> 2, j0 = (t & 3) * 16;
  const u16* src = vh + bh * (NS * NHD) + (s0 + j0) * NHD + d;
  ushort8 a, b;
#pragma unroll
  for (int j = 0; j < 8; j++) a[j] = src[j * NHD];
#pragma unroll
  for (int j = 0; j < 8; j++) b[j] = src[(8 + j) * NHD];
  u16* dst = vt + bh * (NHD * NS) + d * NS + s0 + j0;
  *(ushort8*)dst = a;
  *(ushort8*)(dst + 8) = b;
}

// ---------------- RoPE (in-place on hi/lo pairs) ----------------------------
__global__ void k_rope(const int* __restrict__ pos_ids,
                       u16* __restrict__ qh, u16* __restrict__ ql,
                       u16* __restrict__ kh, u16* __restrict__ kl) {
  int gid = blockIdx.x * 256 + threadIdx.x;
  int row = gid >> 5, d = gid & 31;          // row in [0, B*NH*S)
  int bh = row >> 11, s = row & 2047, b = bh >> 4;
  int pos = pos_ids[b * NS + s];
  float inv = exp2f((float)d * -0.4152410118609203f);
  float fr = (float)pos * inv;
  float c = cosf(fr), sn = sinf(fr);   // precise trig: match np reference
  int off = row * 64 + d;
  {
    float x1 = bf2f(qh[off]) + bf2f(ql[off]);
    float x2 = bf2f(qh[off + 32]) + bf2f(ql[off + 32]);
    float n1 = x1 * c - x2 * sn;
    float n2 = x2 * c + x1 * sn;
    u16 h1 = f2bf(n1); qh[off] = h1;       ql[off] = f2bf(n1 - bf2f(h1));
    u16 h2 = f2bf(n2); qh[off + 32] = h2;  ql[off + 32] = f2bf(n2 - bf2f(h2));
  }
  {
    float x1 = bf2f(kh[off]) + bf2f(kl[off]);
    float x2 = bf2f(kh[off + 32]) + bf2f(kl[off + 32]);
    float n1 = x1 * c - x2 * sn;
    float n2 = x2 * c + x1 * sn;
    u16 h1 = f2bf(n1); kh[off] = h1;       kl[off] = f2bf(n1 - bf2f(h1));
    u16 h2 = f2bf(n2); kh[off + 32] = h2;  kl[off + 32] = f2bf(n2 - bf2f(h2));
  }
}

// ---------------- flash attention with KV-split (flash-decoding) ------------
// 1024 blocks = 32 bh x 16 qt x 2 half. Each block: 16 KV tiles (half range).
// Writes UNNORMALIZED partial O (bf16 hi/lo, token-major layout) + (m,l) f32.
// Swapped-operand 32x32 MFMA; in-register softmax; dbuf K+V LDS staging.
__global__ __launch_bounds__(256) void k_attn(
    const u16* __restrict__ qh, const u16* __restrict__ ql,
    const u16* __restrict__ kh, const u16* __restrict__ kl,
    const u16* __restrict__ vt,
    u16* __restrict__ p0h, u16* __restrict__ p0l,
    u16* __restrict__ p1h, u16* __restrict__ p1l,
    float2* __restrict__ ml0, float2* __restrict__ ml1) {
  __shared__ __attribute__((aligned(16))) char SM[49152];
  const int tid = threadIdx.x, wave = tid >> 6, lane = tid & 63;
  const int l5 = lane & 31, hi = lane >> 5;
  const int bid = blockIdx.x;
  const int swzb = ((bid & 7) << 7) | (bid >> 3);   // XCD-chunked (1024 = 8*128)
  const int half = swzb & 1, qt = (swzb >> 1) & 15, bh = swzb >> 5;
  const int b = bh >> 4, hco = (bh & 15) * NHD;
  const int base = bh * (NS * NHD);
  const int qrow = qt * 128 + wave * 32 + l5;
  const int kbase = half << 10;                     // 1024 keys per half
  const float SC = 0.125f * 1.4426950408889634f;    // log2 domain
  u16* ph = half ? p1h : p0h;
  u16* pl = half ? p1l : p0l;
  float2* mlp = half ? ml1 : ml0;

  // Q B-frags: lane holds Q[qrow][s*16 + hi*8 + j], hi/lo re-split after scale
  bf16x8 qfh[4], qfl[4];
#pragma unroll
  for (int s = 0; s < 4; s++) {
    int off = base + qrow * NHD + s * 16 + hi * 8;
    ushort8 hu = *(const ushort8*)(qh + off);
    ushort8 lu = *(const ushort8*)(ql + off);
    union { ushort8 u; bf16x8 v; } H, L;
#pragma unroll
    for (int j = 0; j < 8; j++) {
      float f = (bf2f(hu[j]) + bf2f(lu[j])) * SC;
      u16 hb = f2bf(f);
      H.u[j] = hb; L.u[j] = f2bf(f - bf2f(hb));
    }
    qfh[s] = H.v; qfl[s] = L.v;
  }

  const floatx16 Z16 = {};   // hoisted zero C-operand (kills per-kt v_movs)
  floatx16 acco[2];
  acco[0] = Z16; acco[1] = Z16;
  float m_r = -1e30f, l_r = 0.f;

  const char* khg0 = (const char*)(kh + base);
  const char* klg0 = (const char*)(kl + base);
  const char* vtg0 = (const char*)(vt + base);   // [64 d-rows][NS], row stride 4096B

#define STAGE_KV(key0_, nb_)                                                     \
  {                                                                              \
    const char* khg = khg0 + (key0_) * 128;                                      \
    const char* klg = klg0 + (key0_) * 128;                                      \
    const char* vtg = vtg0 + (key0_) * 2;                                        \
    _Pragma("unroll")                                                            \
    for (int it = 0; it < 2; ++it) {                                             \
      int L = it * 4096 + tid * 16;                                              \
      int r7 = (L >> 7) & 7;                                                     \
      int g = L ^ (r7 << 4);                                                     \
      gload16(khg + g, SM + (nb_) + it * 4096 + wave * 1024);                    \
      gload16(klg + g, SM + (nb_) + 8192 + it * 4096 + wave * 1024);             \
      int vcol = (L & 127) ^ (r7 << 4);                                          \
      gload16(vtg + (size_t)(L >> 7) * 4096 + vcol,                              \
              SM + (nb_) + 16384 + it * 4096 + wave * 1024);                     \
    }                                                                            \
  }

  // prologue: stage tile 0 of this half into buf 0
  STAGE_KV(kbase, 0);

  for (int kt = 0; kt < 16; ++kt) {
    __syncthreads();   // stage(kt) landed; buf[kt-1] readers done
    const int cb = (kt & 1) * 24576;
    const int key0 = kbase + kt * 64;

    if (kt < 15) {     // stage kt+1 into the other buffer; lands during compute
      STAGE_KV(key0 + 64, ((kt + 1) & 1) * 24576);
    }

    // S^T = K Q^T : 3-term hi/lo, 24 mfma32 (C of first term = hoisted zero)
    floatx16 sacc[2];
#pragma unroll
    for (int t = 0; t < 2; t++) {
      const int row = 32 * t + l5;
      const int swz = (row & 7) << 4;
      {
        int byt = cb + row * 128 + ((hi * 16) ^ swz);
        bf16x8 ah = *(const bf16x8*)(SM + byt);
        bf16x8 al8 = *(const bf16x8*)(SM + 8192 + byt);
        __builtin_amdgcn_s_setprio(1);
        sacc[t] = __builtin_amdgcn_mfma_f32_32x32x16_bf16(ah, qfh[0], Z16, 0, 0, 0);
        sacc[t] = __builtin_amdgcn_mfma_f32_32x32x16_bf16(ah, qfl[0], sacc[t], 0, 0, 0);
        sacc[t] = __builtin_amdgcn_mfma_f32_32x32x16_bf16(al8, qfh[0], sacc[t], 0, 0, 0);
        __builtin_amdgcn_s_setprio(0);
      }
#pragma unroll
      for (int s = 1; s < 4; s++) {
        int byt = cb + row * 128 + ((s * 32 + hi * 16) ^ swz);
        bf16x8 ah = *(const bf16x8*)(SM + byt);
        bf16x8 al8 = *(const bf16x8*)(SM + 8192 + byt);
        __builtin_amdgcn_s_setprio(1);
        sacc[t] = __builtin_amdgcn_mfma_f32_32x32x16_bf16(ah, qfh[s], sacc[t], 0, 0, 0);
        sacc[t] = __builtin_amdgcn_mfma_f32_32x32x16_bf16(ah, qfl[s], sacc[t], 0, 0, 0);
        sacc[t] = __builtin_amdgcn_mfma_f32_32x32x16_bf16(al8, qfh[s], sacc[t], 0, 0, 0);
        __builtin_amdgcn_s_setprio(0);
      }
    }

    // ---- in-register online softmax (lane owns q-row = l5) ----------------
    float mt = fmaxf(tmax16(sacc[0]), tmax16(sacc[1]));
    mt = mergemax(mt);                        // lane<->lane+32 merge
    if (!__all(mt <= m_r + 8.0f)) {           // defer-max (T13)
      float mn = fmaxf(m_r, mt);
      float sc2 = exp2f(m_r - mn);
      l_r *= sc2;
#pragma unroll
      for (int dt = 0; dt < 2; dt++)
#pragma unroll
        for (int r = 0; r < 16; r++) acco[dt][r] *= sc2;
      m_r = mn;
    }
    float s0 = 0.f, s1 = 0.f, s2 = 0.f, s3 = 0.f;  // tree partials (cut dep chain)
#pragma unroll
    for (int t = 0; t < 2; t++)
#pragma unroll
      for (int r = 0; r < 16; r += 4) {
        float p0 = exp2f(sacc[t][r + 0] - m_r);
        float p1 = exp2f(sacc[t][r + 1] - m_r);
        float p2 = exp2f(sacc[t][r + 2] - m_r);
        float p3 = exp2f(sacc[t][r + 3] - m_r);
        sacc[t][r + 0] = p0; sacc[t][r + 1] = p1;
        sacc[t][r + 2] = p2; sacc[t][r + 3] = p3;
        s0 += p0; s1 += p1; s2 += p2; s3 += p3;
      }
    l_r += mergesum((s0 + s1) + (s2 + s3));

    // ---- V^T A-frags from LDS (swizzled ds_read_b128) ---------------------
    bf16x8 vtf[2][4];
#pragma unroll
    for (int dt = 0; dt < 2; dt++) {
      const int vrow = l5 + 32 * dt;
      const int swzv = (vrow & 7) << 4;
#pragma unroll
      for (int s = 0; s < 4; s++)
        vtf[dt][s] = *(const bf16x8*)(SM + cb + 16384 + vrow * 128 + ((s * 32 + hi * 16) ^ swzv));
    }

    // ---- pack P (cvt casts -> v_cvt_pk; permlane32_swap exchange), PV -----
#pragma unroll
    for (int s = 0; s < 4; s++) {
      int t = s >> 1, rb = (s & 1) * 8;
      union { __bf16 bb[8]; unsigned u[4]; } Wp;
#pragma unroll
      for (int j = 0; j < 8; j++) Wp.bb[j] = (__bf16)sacc[t][rb + j];
      uint2v r02 = pl32(Wp.u[0], Wp.u[2]);
      uint2v r13 = pl32(Wp.u[1], Wp.u[3]);
      union { unsigned u[4]; bf16x8 v; } P;
      P.u[0] = r02[0]; P.u[1] = r13[0]; P.u[2] = r02[1]; P.u[3] = r13[1];
      __builtin_amdgcn_s_setprio(1);
      acco[0] = __builtin_amdgcn_mfma_f32_32x32x16_bf16(vtf[0][s], P.v, acco[0], 0, 0, 0);
      acco[1] = __builtin_amdgcn_mfma_f32_32x32x16_bf16(vtf[1][s], P.v, acco[1], 0, 0, 0);
      __builtin_amdgcn_s_setprio(0);
    }
  }

  // per-row (m,l): identical in both half-lanes after merges; hi==0 lanes store
  if (hi == 0) mlp[bh * NS + qrow] = make_float2(m_r, l_r);

  __syncthreads();   // done reading K/V bufs; SM reused for O transpose

  // ---- partial-O write: swizzled LDS transpose -> coalesced hi/lo stores ---
  float* OT = (float*)SM;
#pragma unroll
  for (int dt = 0; dt < 2; dt++)
#pragma unroll
    for (int r = 0; r < 16; r++) {
      int col = (r & 3) + 8 * (r >> 2) + 4 * hi + 32 * dt;  // d
      int cs = (col & 32) | ((col ^ l5) & 31);
      OT[(wave * 32 + l5) * 64 + cs] = acco[dt][r];         // unnormalized
    }
  __syncthreads();
  {
    int row = tid >> 1, h = tid & 1;
    union { u16 s8[8]; ushort8 v; } HB[4], LB[4];
#pragma unroll
    for (int j = 0; j < 32; j++) {
      int c = h * 32 + j;
      int cs = (c & 32) | ((c ^ (row & 31)) & 31);
      float f = OT[row * 64 + cs];
      u16 hb = f2bf(f);
      HB[j >> 3].s8[j & 7] = hb;
      LB[j >> 3].s8[j & 7] = f2bf(f - bf2f(hb));
    }
    size_t doff = ((size_t)(b * NS + qt * 128 + row)) * NHID + hco + h * 32;
#pragma unroll
    for (int q = 0; q < 4; q++) {
      *(ushort8*)(ph + doff + q * 8) = HB[q].v;
      *(ushort8*)(pl + doff + q * 8) = LB[q].v;
    }
  }
}

// ---------------- merge the two KV halves -> normalized O (hi/lo bf16) ------
// In-place safe on p0 (each element read+written by the same thread).
__global__ void k_merge(const u16* __restrict__ p0h, const u16* __restrict__ p0l,
                        const u16* __restrict__ p1h, const u16* __restrict__ p1l,
                        const float2* __restrict__ ml0, const float2* __restrict__ ml1,
                        u16* __restrict__ aoh, u16* __restrict__ aol) {
  int gid = blockIdx.x * 256 + threadIdx.x;   // 524288 total (x8 elems)
  int tok = gid >> 7, c8 = gid & 127;
  int head = c8 >> 3;
  int b = tok >> 11, s = tok & 2047;
  int mlrow = ((b << 4) + head) * NS + s;
  float2 A = ml0[mlrow], Bv = ml1[mlrow];
  float M = fmaxf(A.x, Bv.x);
  float wA = exp2f(A.x - M), wB = exp2f(Bv.x - M);
  float inv = 1.f / (A.y * wA + Bv.y * wB);
  float ca = wA * inv, cb = wB * inv;
  size_t off = (size_t)tok * NHID + c8 * 8;
  ushort8 a_h = *(const ushort8*)(p0h + off);
  ushort8 a_l = *(const ushort8*)(p0l + off);
  ushort8 b_h = *(const ushort8*)(p1h + off);
  ushort8 b_l = *(const ushort8*)(p1l + off);
  union { u16 s8[8]; ushort8 v; } H, L;
#pragma unroll
  for (int j = 0; j < 8; j++) {
    float f = (bf2f(a_h[j]) + bf2f(a_l[j])) * ca + (bf2f(b_h[j]) + bf2f(b_l[j])) * cb;
    u16 hb = f2bf(f);
    H.s8[j] = hb;
    L.s8[j] = f2bf(f - bf2f(hb));
  }
  *(ushort8*)(aoh + off) = H.v;
  *(ushort8*)(aol + off) = L.v;
}

__global__ void k_scale(const double* __restrict__ sums, const float* __restrict__ hss,
                        float* __restrict__ out) {
  if (threadIdx.x == 0) {
    float sv = (float)(sums[2] / (double)WELEM) + 1e-5f;
    float so = (float)(sums[3] / (double)WELEM) + 1e-5f;
    out[NTOK * NHID] = hss[0] * sv * so;
  }
}

extern "C" void kernel_launch(void* const* d_in, const int* in_sizes, int n_in,
                              void* d_out, int out_size, void* d_ws, size_t ws_size,
                              hipStream_t stream) {
  const float* x   = (const float*)d_in[0];
  const float* hss = (const float*)d_in[1];
  const int*   pos = (const int*)d_in[2];
  const float* wq  = (const float*)d_in[3];
  const float* wk  = (const float*)d_in[4];
  const float* wv  = (const float*)d_in[5];
  const float* wo  = (const float*)d_in[6];
  float* out = (float*)d_out;
  char* ws = (char*)d_ws;
  const size_t MB = 1u << 20;
  u16* wt = (u16*)(ws);              // 4 ternary matrices, 8MB
  u16* xh = (u16*)(ws + 8 * MB);
  u16* xl = (u16*)(ws + 16 * MB);
  u16* qh = (u16*)(ws + 24 * MB);
  u16* ql = (u16*)(ws + 32 * MB);
  u16* kh = (u16*)(ws + 40 * MB);
  u16* kl = (u16*)(ws + 48 * MB);
  u16* vh = (u16*)(ws + 56 * MB);    // dead after k_vtrans -> reused as p1h
  u16* vt = (u16*)(ws + 64 * MB);    // transposed V [bh][d][s]
  u16* p1l = (u16*)(ws + 72 * MB);
  float2* ml0 = (float2*)(ws + 80 * MB);            // 512KB
  float2* ml1 = (float2*)(ws + 80 * MB + 512 * 1024);
  double* sums = (double*)(ws + 81 * MB);
  u16* p0h = xh;   // x no longer needed after QKV proj
  u16* p0l = xl;
  u16* p1h = vh;
  u16* aoh = xh;   // merge output (in-place over p0)
  u16* aol = xl;

  k_init<<<1, 64, 0, stream>>>(sums);
  k_abssum<<<dim3(256, 4), 256, 0, stream>>>(wq, wk, wv, wo, sums);
  k_quant<<<dim3(1024, 4), 256, 0, stream>>>(wq, wk, wv, wo, sums, wt);
  k_split<<<4096, 256, 0, stream>>>(x, xh, xl);
  k_gemm<0><<<dim3(32, 8, 3), 256, 0, stream>>>(xh, xl, wt, nullptr, qh, ql, kh, kl, vh);
  k_vtrans<<<dim3(32, 32), 256, 0, stream>>>(vh, vt);
  k_rope<<<8192, 256, 0, stream>>>(pos, qh, ql, kh, kl);
  k_attn<<<1024, 256, 0, stream>>>(qh, ql, kh, kl, vt, p0h, p0l, p1h, p1l, ml0, ml1);
  k_merge<<<2048, 256, 0, stream>>>(p0h, p0l, p1h, p1l, ml0, ml1, aoh, aol);
  k_gemm<1><<<dim3(32, 8, 1), 256, 0, stream>>>(aoh, aol, wt, out,
                                                nullptr, nullptr, nullptr, nullptr, nullptr);
  k_scale<<<1, 64, 0, stream>>>(sums, hss, out);
}